// Round 1
// 1021.413 us; speedup vs baseline: 1.1358x; 1.1358x over previous
//
#include <hip/hip_runtime.h>

typedef unsigned short ushort_t;
typedef unsigned int uint32;
typedef __bf16 bf16x8 __attribute__((ext_vector_type(8)));
typedef float floatx4 __attribute__((ext_vector_type(4)));

#define E_TOTAL 1000000
#define N_TILES 15625   // E / 64 exactly
#define N_NODES 50000

__device__ __forceinline__ ushort_t f2bf(float f) {
  union { float f; uint32 i; } x; x.f = f;
  uint32 i = x.i;
  return (ushort_t)((i + 0x7fffu + ((i >> 16) & 1u)) >> 16);
}

// Repack W1 (k-rows 0..191 only; x_u rows folded into bias) and W2 into
// bf16 MFMA B-fragment-major layout; fold x_u contribution + b1 into bu1 (f32).
__global__ void prep_kernel(const float* __restrict__ W1,
                            const float* __restrict__ W2,
                            const float* __restrict__ b1,
                            const float* __restrict__ xu,
                            ushort_t* __restrict__ W1p,   // 49152 elems
                            ushort_t* __restrict__ W2p,   // 16384 elems
                            float* __restrict__ bu1) {    // 256 floats
  int bid = blockIdx.x;
  int tid = threadIdx.x;
  if (bid < 256) {
    int g = bid * 256 + tid;  // 0..65535
    if (g < 49152) {
      int j = g & 7, l = (g >> 3) & 63, t = g >> 9;
      int kk = t >> 4, gnt = t & 15;
      int k = kk * 32 + ((l >> 4) * 8) + j;
      int n = gnt * 16 + (l & 15);
      W1p[g] = f2bf(W1[k * 256 + n]);
    } else {
      int g2 = g - 49152;
      int j = g2 & 7, l = (g2 >> 3) & 63, t = g2 >> 9;
      int kk = t >> 2, nt = t & 3;
      int k = kk * 32 + ((l >> 4) * 8) + j;
      int n = nt * 16 + (l & 15);
      W2p[g2] = f2bf(W2[k * 64 + n]);
    }
  } else {
    float s = b1[tid];
    for (int k = 0; k < 64; ++k)
      s += xu[k] * W1[(192 + k) * 256 + tid];
    bu1[tid] = s;
  }
}

// f32 -> bf16 table conversion (8 floats per thread), rounding identical to f2bf.
__global__ void conv_kernel(const float* __restrict__ src,
                            ushort_t* __restrict__ dst, int n16) {
  int i = blockIdx.x * 256 + threadIdx.x;
  if (i >= n16) return;
  const float4* s = (const float4*)src + (size_t)i * 2;
  float4 a = s[0], b = s[1];
  uint4 o;
  o.x = (uint32)f2bf(a.x) | ((uint32)f2bf(a.y) << 16);
  o.y = (uint32)f2bf(a.z) | ((uint32)f2bf(a.w) << 16);
  o.z = (uint32)f2bf(b.x) | ((uint32)f2bf(b.y) << 16);
  o.w = (uint32)f2bf(b.z) | ((uint32)f2bf(b.w) << 16);
  ((uint4*)dst)[i] = o;
}

// Prefetch issue: every thread loads 8x16B for tile starting at edge e0n.
// c<8: xs bf16 table, c in 8..15: xt bf16 table, c in 16..31: edge_attr f32.
__device__ __forceinline__ void issue_pf(uint4 (&pf)[8], long e0n,
    int c, int r8, int cj,
    const ushort_t* __restrict__ xsb, const ushort_t* __restrict__ xtb,
    const int* __restrict__ idx, const float* __restrict__ ea) {
  if (c < 16) {
    const ushort_t* tab = (c < 8) ? xsb : xtb;
    const long base = (c < 8) ? 0 : (long)E_TOTAL;
    int coff = c & 7;
#pragma unroll
    for (int p = 0; p < 8; ++p) {
      int r = p * 8 + r8;
      int id = idx[base + e0n + r];
      pf[p] = *(const uint4*)(tab + (size_t)id * 64 + coff * 8);
    }
  } else {
#pragma unroll
    for (int p = 0; p < 8; ++p) {
      int r = p * 8 + r8;
      pf[p] = *(const uint4*)(ea + (size_t)(e0n + r) * 64 + (size_t)cj * 4);
    }
  }
}

#define WAIT_LGKM0() asm volatile("s_waitcnt lgkmcnt(0)" ::: "memory")
#define RAW_BARRIER()                       \
  do {                                      \
    __builtin_amdgcn_sched_barrier(0);      \
    __builtin_amdgcn_s_barrier();           \
    __builtin_amdgcn_sched_barrier(0);      \
  } while (0)

// Pipelined fused kernel: cross-tile register prefetch of gathers (bf16 node
// tables), raw barriers (no vmcnt drain mid-tile), counted vmcnt at loop top.
__global__ __launch_bounds__(256, 2) void fused_pf_kernel(
    const ushort_t* __restrict__ xsb, const ushort_t* __restrict__ xtb,
    const int* __restrict__ idx, const float* __restrict__ ea,
    const ushort_t* __restrict__ W1p, const ushort_t* __restrict__ W2p,
    const float* __restrict__ bu1, const float* __restrict__ b2,
    const float* __restrict__ gamma, float* __restrict__ out) {
  __shared__ uint4 lds_hp4[2048];   // 32 KB: H (64x192 bf16, 384B stride) / P (64x256 bf16, 512B stride)
  __shared__ uint4 lds_w24[2048];   // 32 KB: W2 fragments (bf16)
  char* lds_hp = (char*)lds_hp4;
  char* lds_w2 = (char*)lds_w24;

  const int tid  = threadIdx.x;
  const int wave = tid >> 6;
  const int lane = tid & 63;
  const int q    = lane >> 4;
  const int m16  = lane & 15;

  // W2 fragments -> LDS (once per block)
#pragma unroll
  for (int i = 0; i < 8; ++i)
    lds_w24[tid + i * 256] = ((const uint4*)W2p)[tid + i * 256];

  // W1 fragments -> registers (wave owns n-quarter)
  bf16x8 b1F[6][4];
#pragma unroll
  for (int kk = 0; kk < 6; ++kk)
#pragma unroll
    for (int n = 0; n < 4; ++n)
      b1F[kk][n] = ((const bf16x8*)W1p)[(kk * 16 + wave * 4 + n) * 64 + lane];

  float b1v[4], b2v[4], gv[4];
#pragma unroll
  for (int n = 0; n < 4; ++n)
    b1v[n] = bu1[wave * 64 + n * 16 + m16];
#pragma unroll
  for (int n = 0; n < 4; ++n) {
    b2v[n] = b2[n * 16 + m16];
    gv[n]  = gamma[n * 16 + m16];
  }

  // staging map: 32 chunk-lanes per row, 8 rows per pass, 8 passes
  const int r8 = tid >> 5;   // 0..7
  const int c  = tid & 31;   // 0..31
  const int cj = c - 16;     // ea float4 index when c>=16

  uint4 pf[8];

  __syncthreads();  // W2/LDS visible; drains everything (prologue only)

  // prologue prefetch for first tile
  issue_pf(pf, (long)blockIdx.x * 64, c, r8, cj, xsb, xtb, idx, ea);
  asm volatile("s_waitcnt vmcnt(0)" ::: "memory");  // so loop-top vmcnt(16) is safe on iter 0

  for (int tile = blockIdx.x; tile < N_TILES; tile += gridDim.x) {
    const long e0 = (long)tile * 64;

    // prefetched gathers done (16 newest VMEM ops = this thread's 16 epilogue stores)
    asm volatile("s_waitcnt vmcnt(16) lgkmcnt(0)" ::: "memory");
    RAW_BARRIER();  // A: all waves finished reading P of previous tile

    // ---- stage H tile from prefetch regs (XOR-swizzled 16B chunks, 384B stride)
    if (c < 16) {
#pragma unroll
      for (int p = 0; p < 8; ++p) {
        int r = p * 8 + r8;
        int csw = c ^ (r & 7);
        *(uint4*)(lds_hp + r * 384 + csw * 16) = pf[p];
      }
    } else {
      int ch = 16 + (cj >> 1), ho = (cj & 1) * 8;
#pragma unroll
      for (int p = 0; p < 8; ++p) {
        int r = p * 8 + r8;
        float4 v = __builtin_bit_cast(float4, pf[p]);
        uint2 o;
        o.x = (uint32)f2bf(v.x) | ((uint32)f2bf(v.y) << 16);
        o.y = (uint32)f2bf(v.z) | ((uint32)f2bf(v.w) << 16);
        int csw = ch ^ (r & 7);
        *(uint2*)(lds_hp + r * 384 + csw * 16 + ho) = o;
      }
    }

    // ---- issue next tile's gathers NOW; they stay in flight across the
    // raw barriers below (no vmcnt drain until next loop top).
    int tnext = tile + (int)gridDim.x;
    if (tnext < N_TILES)
      issue_pf(pf, (long)tnext * 64, c, r8, cj, xsb, xtb, idx, ea);

    WAIT_LGKM0();
    RAW_BARRIER();  // B: H visible to all waves

    // ---- layer 1: wave computes all 64 rows x its 64 cols, K=192
    floatx4 acc[4][4];
#pragma unroll
    for (int mt = 0; mt < 4; ++mt)
#pragma unroll
      for (int n = 0; n < 4; ++n)
        acc[mt][n] = (floatx4){0.f, 0.f, 0.f, 0.f};

#pragma unroll
    for (int kk = 0; kk < 6; ++kk) {
      bf16x8 aF[4];
#pragma unroll
      for (int mt = 0; mt < 4; ++mt) {
        int row = mt * 16 + m16;
        int ch  = (kk * 4 + q) ^ (row & 7);
        aF[mt] = *(const bf16x8*)(lds_hp + row * 384 + ch * 16);
      }
#pragma unroll
      for (int mt = 0; mt < 4; ++mt)
#pragma unroll
        for (int n = 0; n < 4; ++n)
          acc[mt][n] = __builtin_amdgcn_mfma_f32_16x16x32_bf16(
              aF[mt], b1F[kk][n], acc[mt][n], 0, 0, 0);
    }

    WAIT_LGKM0();   // our H ds_reads complete before others overwrite
    RAW_BARRIER();  // C: all H reads done before P overwrites buffer

    // ---- bias + LeakyReLU, write P (bf16) to LDS (512B stride, swizzled)
#pragma unroll
    for (int mt = 0; mt < 4; ++mt)
#pragma unroll
      for (int n = 0; n < 4; ++n)
#pragma unroll
        for (int r = 0; r < 4; ++r) {
          float v = acc[mt][n][r] + b1v[n];
          v = (v >= 0.f) ? v : 0.01f * v;
          int row = mt * 16 + q * 4 + r;
          int col = (wave << 6) + n * 16 + m16;
          int ch  = (col >> 3) ^ (row & 7);
          *(ushort_t*)(lds_hp + row * 512 + ch * 16 + (col & 7) * 2) = f2bf(v);
        }

    WAIT_LGKM0();
    RAW_BARRIER();  // D: P visible

    // ---- layer 2: wave computes rows wave*16..+15, all 64 cols, K=256
    floatx4 acc2[4];
#pragma unroll
    for (int n = 0; n < 4; ++n) acc2[n] = (floatx4){0.f, 0.f, 0.f, 0.f};

#pragma unroll
    for (int kk = 0; kk < 8; ++kk) {
      int row = (wave << 4) + m16;
      int ch  = (kk * 4 + q) ^ (row & 7);
      bf16x8 a2 = *(const bf16x8*)(lds_hp + row * 512 + ch * 16);
#pragma unroll
      for (int n = 0; n < 4; ++n) {
        bf16x8 bf = *(const bf16x8*)(lds_w2 + ((kk * 4 + n) * 64 + lane) * 16);
        acc2[n] = __builtin_amdgcn_mfma_f32_16x16x32_bf16(a2, bf, acc2[n], 0, 0, 0);
      }
    }

    // ---- epilogue: +b2, RMSNorm over 64 cols, store f32 (16 stores/thread)
    float vals[4][4];
#pragma unroll
    for (int n = 0; n < 4; ++n)
#pragma unroll
      for (int r = 0; r < 4; ++r)
        vals[n][r] = acc2[n][r] + b2v[n];

#pragma unroll
    for (int r = 0; r < 4; ++r) {
      float ss = 0.f;
#pragma unroll
      for (int n = 0; n < 4; ++n) ss += vals[n][r] * vals[n][r];
#pragma unroll
      for (int m = 1; m < 16; m <<= 1) ss += __shfl_xor(ss, m, 64);
      float rms = rsqrtf(ss * 0.015625f + 1.1920928955078125e-07f);
      long rowg = e0 + (wave << 4) + q * 4 + r;
      float* op = out + rowg * 64 + m16;
#pragma unroll
      for (int n = 0; n < 4; ++n)
        op[n * 16] = vals[n][r] * rms * gv[n];
    }
  }
}

// ------- legacy kernel (fallback when workspace too small for bf16 tables) -------
__global__ __launch_bounds__(256, 2) void fused_kernel(
    const float* __restrict__ xs, const float* __restrict__ xt,
    const int* __restrict__ idx, const float* __restrict__ ea,
    const ushort_t* __restrict__ W1p, const ushort_t* __restrict__ W2p,
    const float* __restrict__ bu1, const float* __restrict__ b2,
    const float* __restrict__ gamma, float* __restrict__ out) {
  __shared__ uint4 lds_hp4[2048];
  __shared__ uint4 lds_w24[2048];
  char* lds_hp = (char*)lds_hp4;
  char* lds_w2 = (char*)lds_w24;

  const int tid  = threadIdx.x;
  const int wave = tid >> 6;
  const int lane = tid & 63;
  const int q    = lane >> 4;
  const int m16  = lane & 15;

#pragma unroll
  for (int i = 0; i < 8; ++i)
    lds_w24[tid + i * 256] = ((const uint4*)W2p)[tid + i * 256];

  bf16x8 b1F[6][4];
#pragma unroll
  for (int kk = 0; kk < 6; ++kk)
#pragma unroll
    for (int n = 0; n < 4; ++n)
      b1F[kk][n] = ((const bf16x8*)W1p)[(kk * 16 + wave * 4 + n) * 64 + lane];

  float b1v[4], b2v[4], gv[4];
#pragma unroll
  for (int n = 0; n < 4; ++n)
    b1v[n] = bu1[wave * 64 + n * 16 + m16];
#pragma unroll
  for (int n = 0; n < 4; ++n) {
    b2v[n] = b2[n * 16 + m16];
    gv[n]  = gamma[n * 16 + m16];
  }

  const int r8  = tid >> 5;
  const int c   = tid & 31;
  const int seg = c >> 3;
  const int off = c & 7;

  for (int tile = blockIdx.x; tile < N_TILES; tile += gridDim.x) {
    const long e0 = (long)tile * 64;
    __syncthreads();

    if (c < 24) {
#pragma unroll
      for (int p = 0; p < 8; ++p) {
        int r = p * 8 + r8;
        long e = e0 + r;
        const float4* sp;
        if (seg == 0)      sp = (const float4*)(xs + (size_t)idx[e] * 64);
        else if (seg == 1) sp = (const float4*)(xt + (size_t)idx[E_TOTAL + e] * 64);
        else               sp = (const float4*)(ea + (size_t)e * 64);
        float4 v0 = sp[off * 2];
        float4 v1 = sp[off * 2 + 1];
        uint4 o;
        o.x = (uint32)f2bf(v0.x) | ((uint32)f2bf(v0.y) << 16);
        o.y = (uint32)f2bf(v0.z) | ((uint32)f2bf(v0.w) << 16);
        o.z = (uint32)f2bf(v1.x) | ((uint32)f2bf(v1.y) << 16);
        o.w = (uint32)f2bf(v1.z) | ((uint32)f2bf(v1.w) << 16);
        int csw = c ^ (r & 7);
        *(uint4*)(lds_hp + r * 384 + csw * 16) = o;
      }
    }
    __syncthreads();

    floatx4 acc[4][4];
#pragma unroll
    for (int mt = 0; mt < 4; ++mt)
#pragma unroll
      for (int n = 0; n < 4; ++n)
        acc[mt][n] = (floatx4){0.f, 0.f, 0.f, 0.f};

#pragma unroll
    for (int kk = 0; kk < 6; ++kk) {
      bf16x8 aF[4];
#pragma unroll
      for (int mt = 0; mt < 4; ++mt) {
        int row = mt * 16 + m16;
        int ch  = (kk * 4 + q) ^ (row & 7);
        aF[mt] = *(const bf16x8*)(lds_hp + row * 384 + ch * 16);
      }
#pragma unroll
      for (int mt = 0; mt < 4; ++mt)
#pragma unroll
        for (int n = 0; n < 4; ++n)
          acc[mt][n] = __builtin_amdgcn_mfma_f32_16x16x32_bf16(
              aF[mt], b1F[kk][n], acc[mt][n], 0, 0, 0);
    }
    __syncthreads();

#pragma unroll
    for (int mt = 0; mt < 4; ++mt)
#pragma unroll
      for (int n = 0; n < 4; ++n)
#pragma unroll
        for (int r = 0; r < 4; ++r) {
          float v = acc[mt][n][r] + b1v[n];
          v = (v >= 0.f) ? v : 0.01f * v;
          int row = mt * 16 + q * 4 + r;
          int col = (wave << 6) + n * 16 + m16;
          int ch  = (col >> 3) ^ (row & 7);
          *(ushort_t*)(lds_hp + row * 512 + ch * 16 + (col & 7) * 2) = f2bf(v);
        }
    __syncthreads();

    floatx4 acc2[4];
#pragma unroll
    for (int n = 0; n < 4; ++n) acc2[n] = (floatx4){0.f, 0.f, 0.f, 0.f};

#pragma unroll
    for (int kk = 0; kk < 8; ++kk) {
      int row = (wave << 4) + m16;
      int ch  = (kk * 4 + q) ^ (row & 7);
      bf16x8 a2 = *(const bf16x8*)(lds_hp + row * 512 + ch * 16);
#pragma unroll
      for (int n = 0; n < 4; ++n) {
        bf16x8 bf = *(const bf16x8*)(lds_w2 + ((kk * 4 + n) * 64 + lane) * 16);
        acc2[n] = __builtin_amdgcn_mfma_f32_16x16x32_bf16(a2, bf, acc2[n], 0, 0, 0);
      }
    }

    float vals[4][4];
#pragma unroll
    for (int n = 0; n < 4; ++n)
#pragma unroll
      for (int r = 0; r < 4; ++r)
        vals[n][r] = acc2[n][r] + b2v[n];

#pragma unroll
    for (int r = 0; r < 4; ++r) {
      float ss = 0.f;
#pragma unroll
      for (int n = 0; n < 4; ++n) ss += vals[n][r] * vals[n][r];
#pragma unroll
      for (int m = 1; m < 16; m <<= 1) ss += __shfl_xor(ss, m, 64);
      float rms = rsqrtf(ss * 0.015625f + 1.1920928955078125e-07f);
      long rowg = e0 + (wave << 4) + q * 4 + r;
      float* op = out + rowg * 64 + m16;
#pragma unroll
      for (int n = 0; n < 4; ++n)
        op[n * 16] = vals[n][r] * rms * gv[n];
    }
  }
}

extern "C" void kernel_launch(void* const* d_in, const int* in_sizes, int n_in,
                              void* d_out, int out_size, void* d_ws, size_t ws_size,
                              hipStream_t stream) {
  const float* xs    = (const float*)d_in[0];
  const float* xt    = (const float*)d_in[1];
  const int*   idx   = (const int*)d_in[2];
  const float* ea    = (const float*)d_in[3];
  const float* xu    = (const float*)d_in[4];
  const float* W1    = (const float*)d_in[5];
  const float* b1    = (const float*)d_in[6];
  const float* W2    = (const float*)d_in[7];
  const float* b2    = (const float*)d_in[8];
  const float* gamma = (const float*)d_in[9];
  float* out = (float*)d_out;

  ushort_t* W1p = (ushort_t*)d_ws;                // 49152 * 2 B
  ushort_t* W2p = W1p + 49152;                    // 16384 * 2 B
  float*    bu1 = (float*)((char*)d_ws + 131072); // 256 * 4 B, ends at 132096

  const size_t TBL_OFF = 132096;                  // 16B aligned
  const size_t TBL_BYTES = (size_t)N_NODES * 64 * 2;  // 6.4 MB per table
  const size_t REQ = TBL_OFF + 2 * TBL_BYTES;     // ~12.93 MB

  prep_kernel<<<257, 256, 0, stream>>>(W1, W2, b1, xu, W1p, W2p, bu1);

  if (ws_size >= REQ) {
    ushort_t* xsb = (ushort_t*)((char*)d_ws + TBL_OFF);
    ushort_t* xtb = xsb + (size_t)N_NODES * 64;
    const int n16 = N_NODES * 64 / 8;             // 400000
    const int cgrid = (n16 + 255) / 256;          // 1563
    conv_kernel<<<cgrid, 256, 0, stream>>>(xs, xsb, n16);
    conv_kernel<<<cgrid, 256, 0, stream>>>(xt, xtb, n16);
    fused_pf_kernel<<<512, 256, 0, stream>>>(xsb, xtb, idx, ea, W1p, W2p,
                                             bu1, b2, gamma, out);
  } else {
    fused_kernel<<<512, 256, 0, stream>>>(xs, xt, idx, ea, W1p, W2p,
                                          bu1, b2, gamma, out);
  }
}